// Round 9
// baseline (9.738 us; speedup 1.0000x reference)
//
#include <hip/hip_runtime.h>

// Two-stage hierarchical probe, 8 rows per 64-lane wave, 8-lane group/row.
// Stage A (always):  j<4 -> row[j*4 .. j*4+3]           (front 16 = 64B line)
//                    j>=4 -> row[D-16+(j-4)*4 .. +3]    (back  16 = 64B line)
// Stage B (rare, P=2^-16/end): the NEXT 16 floats at each end — ONE extra
//   HBM round-trip for ~2 of 65536 rows, hidden under the bulk.
// Full-scan fallback only after both stages miss (P=2^-32/end, ~never).
// Rounds 4/5 lesson: a serialized full-scan straggler costs ~24us; round 6
// fixed it by width (128B/end); this round tests whether 64B/end halves
// FETCH_SIZE (TCC line 64B) or not (128B line -> round-6 config is floor).
__global__ __launch_bounds__(256) void nby2_reverse_kernel(
        const float* __restrict__ x,
        const int* __restrict__ vrange_p,
        float* __restrict__ out,
        int N, int D) {
    const int lane   = threadIdx.x & 63;
    const int wave   = (blockIdx.x * blockDim.x + threadIdx.x) >> 6;
    const int g      = lane >> 3;     // row-group within wave (0..7)
    const int j      = lane & 7;      // lane within group
    const int row_id = wave * 8 + g;
    if (row_id >= N) return;

    const int vr = *vrange_p;         // uniform scalar load, issued early
    const float* __restrict__ row = x + (size_t)row_id * (size_t)D;

    const int BIG = 0x7fffffff;
    int fval = BIG;                   // candidate 'first'
    int lval = -1;                    // candidate 'last'
    const bool vec_ok = ((D & 3) == 0);

    if (D >= 32 && vec_ok) {
        // ---- stage A: front 16 + back 16 (one float4 per lane) ----
        const int baseA = (j < 4) ? (j * 4) : (D - 16 + (j - 4) * 4);
        const float4 v = *reinterpret_cast<const float4*>(row + baseA);
        const unsigned m = (v.x >= 0.f ? 1u : 0u) | (v.y >= 0.f ? 2u : 0u)
                         | (v.z >= 0.f ? 4u : 0u) | (v.w >= 0.f ? 8u : 0u);
        if (m) {
            if (j < 4) fval = baseA + __builtin_ctz(m);
            else       lval = baseA + 31 - __builtin_clz(m);
        }
        #pragma unroll
        for (int d = 1; d < 8; d <<= 1) {
            fval = min(fval, __shfl_xor(fval, d));
            lval = max(lval, __shfl_xor(lval, d));
        }

        if (fval == BIG || lval < 0) {
            // ---- stage B (rare): next 16 floats at each end ----
            const int baseB = (j < 4) ? (16 + j * 4) : (D - 32 + (j - 4) * 4);
            const float4 w = *reinterpret_cast<const float4*>(row + baseB);
            const unsigned mb = (w.x >= 0.f ? 1u : 0u) | (w.y >= 0.f ? 2u : 0u)
                              | (w.z >= 0.f ? 4u : 0u) | (w.w >= 0.f ? 8u : 0u);
            int f2 = BIG, l2 = -1;
            if (mb) {
                if (j < 4) f2 = baseB + __builtin_ctz(mb);
                else       l2 = baseB + 31 - __builtin_clz(mb);
            }
            #pragma unroll
            for (int d = 1; d < 8; d <<= 1) {
                f2 = min(f2, __shfl_xor(f2, d));
                l2 = max(l2, __shfl_xor(l2, d));
            }
            // Merge with priority: stage-A front < stage-B front (min keeps A);
            // stage-A back > stage-B back (max keeps A).
            fval = min(fval, f2);
            lval = max(lval, l2);
        }
    }

    if (fval == BIG || lval < 0) {    // ~never taken (P=2^-32 per end)
        int lf = BIG, ll = -1;
        if (vec_ok) {
            const int T = D & ~31;
            for (int i = j * 4; i < T; i += 32) {
                const float4 v = *reinterpret_cast<const float4*>(row + i);
                const unsigned m = (v.x >= 0.f ? 1u : 0u) | (v.y >= 0.f ? 2u : 0u)
                                 | (v.z >= 0.f ? 4u : 0u) | (v.w >= 0.f ? 8u : 0u);
                if (m) {
                    lf = min(lf, i + __builtin_ctz(m));
                    ll = max(ll, i + 31 - __builtin_clz(m));
                }
            }
            for (int i = T + j; i < D; i += 8) {
                if (row[i] >= 0.f) { lf = min(lf, i); ll = max(ll, i); }
            }
        } else {
            for (int i = j; i < D; i += 8) {
                if (row[i] >= 0.f) { lf = min(lf, i); ll = max(ll, i); }
            }
        }
        #pragma unroll
        for (int d = 1; d < 8; d <<= 1) {
            lf = min(lf, __shfl_xor(lf, d));
            ll = max(ll, __shfl_xor(ll, d));
        }
        fval = min(fval, lf);
        lval = max(lval, ll);
        if (fval == BIG) {            // all-negative row
            if (j == 0) out[row_id] = 0.0f;
            return;
        }
    }

    if (j == 0) {
        const int bits = vr >> 1;
        out[row_id] = (float)(2 * bits - fval - lval - 1);
    }
}

extern "C" void kernel_launch(void* const* d_in, const int* in_sizes, int n_in,
                              void* d_out, int out_size, void* d_ws, size_t ws_size,
                              hipStream_t stream) {
    const float* x = (const float*)d_in[0];
    const int* vrange_p = (const int*)d_in[1];
    float* out = (float*)d_out;

    const int N = out_size;                   // 65536 rows
    const int D = in_sizes[0] / out_size;     // 2048 cols

    const int rows_per_block = 32;            // 4 waves * 8 rows = 256 threads
    const int grid = (N + rows_per_block - 1) / rows_per_block;  // 2048 WGs

    nby2_reverse_kernel<<<grid, 256, 0, stream>>>(x, vrange_p, out, N, D);
}